// Round 2
// baseline (255.981 us; speedup 1.0000x reference)
//
#include <hip/hip_runtime.h>

#define R_TOTAL 12544
#define NTOK    784
#define CDIM    384
#define INNER   1152
#define NHEAD   8
#define HDIM    48
#define BATCH   16
#define HSEG    37632                  // 784*48 elements per (b,h,part) panel
#define SCALE   0.14433756729740643f   // 48^-0.5
#define LOG2E   1.4426950408889634f
#define SCLOG2E 0.20823509f            // SCALE * LOG2E (folded into K's BN affine)

typedef unsigned short u16;
typedef unsigned int   u32;
typedef __attribute__((ext_vector_type(8))) short short8;   // 8 bf16, 4 VGPRs
typedef __attribute__((ext_vector_type(4))) float floatx4;  // MFMA C/D

union V8 { uint4 u; short8 s; u16 h[8]; };

// workspace layout (BYTE offsets) — total 38.56 MB, byte-identical to prior rounds.
// Yb is HEAD-MAJOR: [b][h][{q,k,v}] panels of HSEG elements each.
//   q,k panels: [n=784][d=48] row-major
//   v panel:    TRANSPOSED [d=48][n=784]  (attention PV A-frags load directly)
#define OB_OFF     28901376ull   // Ob bf16 [12544,384]
#define ST_OFF     38535168ull   // fp32 stats: S1[2304] AB1[2304] S2[768] AB2[768]

__device__ __forceinline__ float b2f(u16 u) {
    union { float f; u32 i; } v; v.i = ((u32)u) << 16; return v.f;
}
__device__ __forceinline__ u16 f2b(float f) {
    union { float f; u32 i; } v; v.f = f;
    u32 r = v.i + 0x7FFFu + ((v.i >> 16) & 1u);   // RNE
    return (u16)(r >> 16);
}
// pack two fp32 -> two bf16 (RNE) in one v_perm_b32
__device__ __forceinline__ u32 pk2(float lo, float hi) {
    union { float f; u32 i; } a, b; a.f = lo; b.f = hi;
    u32 ra = a.i + 0x7FFFu + ((a.i >> 16) & 1u);
    u32 rb = b.i + 0x7FFFu + ((b.i >> 16) & 1u);
    return __builtin_amdgcn_perm(rb, ra, 0x07060302u);   // [rb.hi16 : ra.hi16]
}
__device__ __forceinline__ float hswish_f(float v) {
    return v * fminf(fmaxf(v + 3.f, 0.f), 6.f) * (1.f / 6.f);
}

__global__ __launch_bounds__(256) void zero_k(float* __restrict__ p, int n) {
    int i = blockIdx.x * 256 + threadIdx.x;
    if (i < n) p[i] = 0.f;
}

// ---------------------------------------------------------------- MFMA GEMM (+fused BN col stats)
// HEADM: store bf16 output in head-major layout (GEMM1 -> attention); V part transposed.
template<int ABF16, int HSW, int OBF16, int HEADM>
__global__ __launch_bounds__(256) void gemm_mfma_k(
    const void* __restrict__ Ap, const float* __restrict__ Bfp,
    void* __restrict__ Cp, float* __restrict__ sums, int M, int Nout, int K)
{
    __shared__ u16 As[128 * 40];
    __shared__ u16 Bs[128 * 40];
    const int t = threadIdx.x;
    const int lane = t & 63, wv = t >> 6;
    const int l15 = lane & 15, quad = lane >> 4;
    const int wm = (wv & 1) * 64, wn = (wv >> 1) * 64;
    const int m0 = blockIdx.y * 128, n0 = blockIdx.x * 128;
    const floatx4 zf = {0.f, 0.f, 0.f, 0.f};

    floatx4 acc[4][4];
    #pragma unroll
    for (int i = 0; i < 4; i++)
        #pragma unroll
        for (int j = 0; j < 4; j++) acc[i][j] = zf;

    for (int k0 = 0; k0 < K; k0 += 32) {
        __syncthreads();
        #pragma unroll
        for (int it = 0; it < 2; it++) {
            const int flat = t + it * 256;
            const int rr = flat >> 2, ss = (flat & 3) * 8;
            uint4 aw;
            if (ABF16) {
                uint4 u = *(const uint4*)((const u16*)Ap + (size_t)(m0 + rr) * K + k0 + ss);
                if (HSW) {
                    aw.x = pk2(hswish_f(b2f((u16)(u.x & 0xffff))), hswish_f(b2f((u16)(u.x >> 16))));
                    aw.y = pk2(hswish_f(b2f((u16)(u.y & 0xffff))), hswish_f(b2f((u16)(u.y >> 16))));
                    aw.z = pk2(hswish_f(b2f((u16)(u.z & 0xffff))), hswish_f(b2f((u16)(u.z >> 16))));
                    aw.w = pk2(hswish_f(b2f((u16)(u.w & 0xffff))), hswish_f(b2f((u16)(u.w >> 16))));
                } else {
                    aw = u;
                }
            } else {
                const float* p = (const float*)Ap + (size_t)(m0 + rr) * K + k0 + ss;
                float4 f0 = *(const float4*)p, f1 = *(const float4*)(p + 4);
                aw.x = pk2(f0.x, f0.y); aw.y = pk2(f0.z, f0.w);
                aw.z = pk2(f1.x, f1.y); aw.w = pk2(f1.z, f1.w);
            }
            *(uint4*)&As[rr * 40 + ss] = aw;
            const float* q = Bfp + (size_t)(n0 + rr) * K + k0 + ss;
            float4 g0 = *(const float4*)q, g1 = *(const float4*)(q + 4);
            uint4 bw;
            bw.x = pk2(g0.x, g0.y); bw.y = pk2(g0.z, g0.w);
            bw.z = pk2(g1.x, g1.y); bw.w = pk2(g1.z, g1.w);
            *(uint4*)&Bs[rr * 40 + ss] = bw;
        }
        __syncthreads();
        short8 af[4], bfr[4];
        #pragma unroll
        for (int mi = 0; mi < 4; mi++)
            af[mi] = *(const short8*)&As[(wm + mi * 16 + l15) * 40 + quad * 8];
        #pragma unroll
        for (int ni = 0; ni < 4; ni++)
            bfr[ni] = *(const short8*)&Bs[(wn + ni * 16 + l15) * 40 + quad * 8];
        #pragma unroll
        for (int mi = 0; mi < 4; mi++)
            #pragma unroll
            for (int ni = 0; ni < 4; ni++)
                acc[mi][ni] = __builtin_amdgcn_mfma_f32_16x16x32_bf16(af[mi], bfr[ni], acc[mi][ni], 0, 0, 0);
    }

    float cs[4] = {0.f, 0.f, 0.f, 0.f}, cq[4] = {0.f, 0.f, 0.f, 0.f};
    #pragma unroll
    for (int mi = 0; mi < 4; mi++) {
        const int mbase = m0 + wm + mi * 16 + quad * 4;
        int bb_[4], nn_[4];
        if (HEADM) {
            #pragma unroll
            for (int reg = 0; reg < 4; reg++) {
                int m = mbase + reg;
                int bv = ((m >> 4) * 1338) >> 16;   // m/784 for m<12544 (=16*49; x/49=(x*1338)>>16)
                bb_[reg] = bv;
                nn_[reg] = m - bv * 784;
            }
        }
        #pragma unroll
        for (int ni = 0; ni < 4; ni++) {
            const int c0 = n0 + wn + ni * 16;      // wave-uniform; 16-col group never straddles h
            const int n = c0 + l15;
            int part = 0, hcol = 0, d0 = 0;
            if (HEADM) {
                part = c0 / 384;
                int rem = c0 - part * 384;
                hcol = rem / 48;
                d0 = rem - hcol * 48;
            }
            if (HEADM && part == 2) {
                // V panel TRANSPOSED: [d][n]; 4 regs = 4 consecutive n (same b: mbase%4==0, 784%4==0)
                u32 w0 = pk2(acc[mi][ni][0], acc[mi][ni][1]);
                u32 w1 = pk2(acc[mi][ni][2], acc[mi][ni][3]);
                size_t off = (size_t)((bb_[0] * 8 + hcol) * 3 + 2) * HSEG
                           + (size_t)(d0 + l15) * NTOK + nn_[0];
                *(uint2*)((u16*)Cp + off) = make_uint2(w0, w1);
                float v0 = b2f((u16)(w0 & 0xffff)), v1 = b2f((u16)(w0 >> 16));
                float v2 = b2f((u16)(w1 & 0xffff)), v3 = b2f((u16)(w1 >> 16));
                cs[ni] += (v0 + v1) + (v2 + v3);
                cq[ni] += (v0 * v0 + v1 * v1) + (v2 * v2 + v3 * v3);
            } else {
                #pragma unroll
                for (int reg = 0; reg < 4; reg++) {
                    float v = acc[mi][ni][reg];
                    float vv;
                    if (OBF16) {
                        u16 hv = f2b(v);
                        size_t off;
                        if (HEADM)
                            off = (size_t)((bb_[reg] * 8 + hcol) * 3 + part) * HSEG
                                + (size_t)nn_[reg] * 48 + d0 + l15;
                        else
                            off = (size_t)(mbase + reg) * Nout + n;
                        ((u16*)Cp)[off] = hv;
                        vv = b2f(hv);
                    } else {
                        ((float*)Cp)[(size_t)(mbase + reg) * Nout + n] = v;
                        vv = v;
                    }
                    cs[ni] += vv;
                    cq[ni] += vv * vv;
                }
            }
        }
    }
    #pragma unroll
    for (int ni = 0; ni < 4; ni++) {
        float s = cs[ni], sq = cq[ni];
        s  += __shfl_xor(s, 16);  s  += __shfl_xor(s, 32);
        sq += __shfl_xor(sq, 16); sq += __shfl_xor(sq, 32);
        if (quad == 0) {
            int col = n0 + wn + ni * 16 + l15;
            atomicAdd(&sums[col], s);
            atomicAdd(&sums[Nout + col], sq);
        }
    }
}

// sc0..sc1: logical-column range whose affine is pre-scaled by sfac (K cols: SCALE*log2e)
__global__ __launch_bounds__(256) void finalize_bn_k(
    const float* __restrict__ sums, const float* __restrict__ g,
    const float* __restrict__ bvec, float* __restrict__ ab, int Ncols, float invM,
    int sc0, int sc1, float sfac)
{
    int c = blockIdx.x * 256 + threadIdx.x;
    if (c >= Ncols) return;
    float mean = sums[c] * invM;
    float var  = sums[Ncols + c] * invM - mean * mean;
    float a    = g[c] * rsqrtf(var + 1e-5f);
    float f    = (c >= sc0 && c < sc1) ? sfac : 1.f;
    ab[c] = a * f;
    ab[Ncols + c] = (bvec[c] - mean * a) * f;
}

__global__ __launch_bounds__(256) void bn_apply_k(
    float* __restrict__ Z, const float* __restrict__ ab, int Ncols, int total4)
{
    for (int i4 = blockIdx.x * 256 + threadIdx.x; i4 < total4; i4 += gridDim.x * 256) {
        int col = (i4 * 4) % Ncols;
        float4 z  = *(float4*)(Z + (size_t)i4 * 4);
        float4 a4 = *(const float4*)(ab + col);
        float4 b4 = *(const float4*)(ab + Ncols + col);
        z.x = a4.x * z.x + b4.x; z.y = a4.y * z.y + b4.y;
        z.z = a4.z * z.z + b4.z; z.w = a4.w * z.w + b4.w;
        *(float4*)(Z + (size_t)i4 * 4) = z;
    }
}

// bf16 in-place BN apply over HEAD-MAJOR Y: logical col derived from physical index.
// q,k panels: [n][d]; v panel: TRANSPOSED [d][n] (8 consecutive elems share one d/col).
__global__ __launch_bounds__(256) void bn_apply_bf16_k(
    u16* __restrict__ Z, const float* __restrict__ ab, int total8)
{
    int i8 = blockIdx.x * 256 + threadIdx.x;
    if (i8 >= total8) return;
    int e0  = i8 * 8;
    int seg = e0 / HSEG;                 // (b*8+h)*3 + part
    int rem = e0 - seg * HSEG;
    int part = seg % 3;
    int hh   = (seg / 3) & 7;
    uint4 u = *(uint4*)(Z + (size_t)i8 * 8);
    uint4 o;
    if (part == 2) {
        int dd  = rem / NTOK;            // row d (8 consecutive n in one d row)
        int col = 2 * 384 + hh * 48 + dd;
        float a = ab[col], bb = ab[1152 + col];
        o.x = pk2(fmaf(b2f((u16)(u.x & 0xffff)), a, bb), fmaf(b2f((u16)(u.x >> 16)), a, bb));
        o.y = pk2(fmaf(b2f((u16)(u.y & 0xffff)), a, bb), fmaf(b2f((u16)(u.y >> 16)), a, bb));
        o.z = pk2(fmaf(b2f((u16)(u.z & 0xffff)), a, bb), fmaf(b2f((u16)(u.z >> 16)), a, bb));
        o.w = pk2(fmaf(b2f((u16)(u.w & 0xffff)), a, bb), fmaf(b2f((u16)(u.w >> 16)), a, bb));
    } else {
        int d0  = rem % 48;
        int col = part * 384 + hh * 48 + d0;
        float4 A0 = *(const float4*)(ab + col),        A1 = *(const float4*)(ab + col + 4);
        float4 B0 = *(const float4*)(ab + 1152 + col), B1 = *(const float4*)(ab + 1152 + col + 4);
        o.x = pk2(fmaf(b2f((u16)(u.x & 0xffff)), A0.x, B0.x), fmaf(b2f((u16)(u.x >> 16)), A0.y, B0.y));
        o.y = pk2(fmaf(b2f((u16)(u.y & 0xffff)), A0.z, B0.z), fmaf(b2f((u16)(u.y >> 16)), A0.w, B0.w));
        o.z = pk2(fmaf(b2f((u16)(u.z & 0xffff)), A1.x, B1.x), fmaf(b2f((u16)(u.z >> 16)), A1.y, B1.y));
        o.w = pk2(fmaf(b2f((u16)(u.w & 0xffff)), A1.z, B1.z), fmaf(b2f((u16)(u.w >> 16)), A1.w, B1.w));
    }
    *(uint4*)(Z + (size_t)i8 * 8) = o;
}

// ---------------------------------------------------------------- MFMA flash attention v9
// TLP-oriented: one 16-row q-fragment per wave, 64 q-rows per block, grid (128,13)=1664 blocks.
// No software K prefetch (resident-wave TLP hides VMEM latency instead); barrier-free main loop.
// __launch_bounds__(256,5): cap VGPRs so 5 waves/SIMD can co-reside.
__global__ __launch_bounds__(256, 5) void attn_mfma_k(
    const u16* __restrict__ Y,
    const float* __restrict__ biases, const int* __restrict__ idxs,
    u16* __restrict__ O)
{
    __shared__ u16 psm[4][64 * 8 * 2];      // per-wave P^T (2 KB each, 8 KB total)
    __shared__ float hb[NTOK];              // biases[h] * LOG2E

    const int t = threadIdx.x;
    const int lane = t & 63, wv = t >> 6;
    const int l15 = lane & 15, quad = lane >> 4;
    const int bh = blockIdx.x;
    const int b = bh >> 3, h = bh & 7;
    const int n0 = blockIdx.y * 64;         // 64 q rows per block (16 per wave)
    const int bN = b * NTOK;
    const floatx4 zf = {0.f, 0.f, 0.f, 0.f};

    const u16* Qb = Y + (size_t)(bh * 3) * HSEG;
    const u16* Kb = Qb + HSEG;
    const u16* Vb = Qb + 2 * HSEG;          // TRANSPOSED [48][784]

    if (t < 196) {
        float4 v = *(const float4*)(biases + (size_t)h * NTOK + (t << 2));
        v.x *= LOG2E; v.y *= LOG2E; v.z *= LOG2E; v.w *= LOG2E;
        *(float4*)&hb[t << 2] = v;
    }

    const int qv = n0 + wv * 16 + l15;
    const int qr = qv < NTOK ? qv : NTOK - 1;
    const int* idxrow = idxs + (size_t)qr * NTOK;

    // Q B-frags: B[k=d][n=q=l15]; chunk1 zero for quad>=2 (d pad 48..63)
    short8 qf[2];
    {
        V8 a0, a1;
        a1.u = make_uint4(0u, 0u, 0u, 0u);
        const u16* src = Qb + (size_t)qr * 48;
        a0.u = *(const uint4*)(src + quad * 8);
        if (quad < 2) a1.u = *(const uint4*)(src + 32 + quad * 8);
        qf[0] = a0.s; qf[1] = a1.s;
    }

    float lsum = 0.f;
    floatx4 oacc[3];
    #pragma unroll
    for (int i = 0; i < 3; i++) oacc[i] = zf;

    const int psbase = ((quad >> 1) * 16 + l15) * 8 + (quad & 1) * 4;

    __syncthreads();   // hb staged; the ONLY barrier in this kernel

    for (int mt = 0; mt < 13; mt++) {
        const int m0k = mt * 64;
        const bool tail = (m0k == 768);

        // ---- idx gathers for THIS tile (issued first; consumed after QK)
        int4 ivc[4];
        #pragma unroll
        for (int sub = 0; sub < 4; sub++) {
            int kb = m0k + sub * 16 + quad * 4;
            kb = kb < NTOK - 4 ? kb : NTOK - 4;
            ivc[sub] = *(const int4*)(idxrow + kb);
        }

        // ---- K A-frags for THIS tile (no SW prefetch; TLP hides latency)
        V8 kfr[4][2];
        #pragma unroll
        for (int sub = 0; sub < 4; sub++) {
            int key = m0k + sub * 16 + l15;
            int kr  = key < NTOK ? key : NTOK - 1;
            const u16* src = Kb + (size_t)kr * 48;
            kfr[sub][0].u = *(const uint4*)(src + quad * 8);
            kfr[sub][1].u = *(const uint4*)(src + 32 + quad * 8);
        }

        // ---- V^T A-frags for THIS tile (consumed at PV)
        // A[m=d=l15][k=key=quad*8+j]. Tail: keys>=784 -> clamp addr to key 0 (P=0 there).
        short8 vfr[2][3];
        #pragma unroll
        for (int kc = 0; kc < 2; kc++) {
            int kk = m0k + kc * 32 + quad * 8;
            kk = kk <= NTOK - 8 ? kk : 0;
            #pragma unroll
            for (int ns = 0; ns < 3; ns++)
                vfr[kc][ns] = *(const short8*)(Vb + (size_t)(ns * 16 + l15) * NTOK + kk);
        }

        // ---- S^T = K*Q^T
        floatx4 sf[4];
        #pragma unroll
        for (int sub = 0; sub < 4; sub++) {
            floatx4 c = zf;
            c = __builtin_amdgcn_mfma_f32_16x16x32_bf16(kfr[sub][0].s, qf[0], c, 0, 0, 0);
            c = __builtin_amdgcn_mfma_f32_16x16x32_bf16(kfr[sub][1].s, qf[1], c, 0, 0, 0);
            sf[sub] = c;
        }

        // ---- p = 2^(s + bias)
        #pragma unroll
        for (int sub = 0; sub < 4; sub++) {
            const int4 iv = ivc[sub];
            float a0 = sf[sub][0] + hb[iv.x];
            float a1 = sf[sub][1] + hb[iv.y];
            float a2 = sf[sub][2] + hb[iv.z];
            float a3 = sf[sub][3] + hb[iv.w];
            float pr[4];
            asm("v_exp_f32 %0, %1" : "=v"(pr[0]) : "v"(a0));
            asm("v_exp_f32 %0, %1" : "=v"(pr[1]) : "v"(a1));
            asm("v_exp_f32 %0, %1" : "=v"(pr[2]) : "v"(a2));
            asm("v_exp_f32 %0, %1" : "=v"(pr[3]) : "v"(a3));
            if (tail) {   // only tile 12 has keys >= 784
                const int kb0 = m0k + sub * 16 + quad * 4;
                #pragma unroll
                for (int reg = 0; reg < 4; reg++)
                    if (kb0 + reg >= NTOK) pr[reg] = 0.f;
            }
            lsum += (pr[0] + pr[1]) + (pr[2] + pr[3]);
            int addr = psbase + (sub >> 1) * 512 + (sub & 1) * 256;
            *(uint2*)&psm[wv][addr] = make_uint2(pk2(pr[0], pr[1]), pk2(pr[2], pr[3]));
        }

        // ---- O^T += V^T * P^T (wave-local LDS, no barrier)
        #pragma unroll
        for (int kc = 0; kc < 2; kc++) {
            short8 pb = *(const short8*)&psm[wv][(kc * 64 + lane) * 8];
            #pragma unroll
            for (int ns = 0; ns < 3; ns++)
                oacc[ns] = __builtin_amdgcn_mfma_f32_16x16x32_bf16(vfr[kc][ns], pb, oacc[ns], 0, 0, 0);
        }
    }

    // ---- epilogue (Ob stays row-major [12544,384] for GEMM2)
    {
        float ls = lsum;
        ls += __shfl_xor(ls, 16);
        ls += __shfl_xor(ls, 32);
        if (qv < NTOK) {
            float rl = 1.f / ls;
            u16* dst = O + (size_t)(bN + qv) * CDIM + h * HDIM;
            #pragma unroll
            for (int ns = 0; ns < 3; ns++)
                #pragma unroll
                for (int reg = 0; reg < 4; reg++)
                    dst[ns * 16 + quad * 4 + reg] = f2b(hswish_f(oacc[ns][reg] * rl));
        }
    }
}

// ---------------------------------------------------------------- launch
extern "C" void kernel_launch(void* const* d_in, const int* in_sizes, int n_in,
                              void* d_out, int out_size, void* d_ws, size_t ws_size,
                              hipStream_t stream)
{
    const float* x     = (const float*)d_in[0];
    const float* Wqkv  = (const float*)d_in[1];
    const float* g1    = (const float*)d_in[2];
    const float* b1    = (const float*)d_in[3];
    const float* Wproj = (const float*)d_in[4];
    const float* g2    = (const float*)d_in[5];
    const float* b2    = (const float*)d_in[6];
    const float* bias  = (const float*)d_in[7];
    const int*   idxs  = (const int*)d_in[8];
    float* out = (float*)d_out;
    char*  wsb = (char*)d_ws;

    u16*   Yb  = (u16*)wsb;
    u16*   Ob  = (u16*)(wsb + OB_OFF);
    float* S1  = (float*)(wsb + ST_OFF);
    float* AB1 = S1 + 2304;
    float* S2  = AB1 + 2304;
    float* AB2 = S2 + 768;

    zero_k<<<24, 256, 0, stream>>>(S1, 6144);

    // GEMM1 (+fused BN1 stats), head-major output, V panels transposed
    gemm_mfma_k<0, 0, 1, 1><<<dim3(INNER / 128, R_TOTAL / 128), 256, 0, stream>>>(
        x, Wqkv, Yb, S1, R_TOTAL, INNER, CDIM);

    finalize_bn_k<<<(INNER + 255) / 256, 256, 0, stream>>>(
        S1, g1, b1, AB1, INNER, 1.f / R_TOTAL, CDIM, 2 * CDIM, SCLOG2E);
    bn_apply_bf16_k<<<(R_TOTAL * INNER / 8 + 255) / 256, 256, 0, stream>>>(
        Yb, AB1, R_TOTAL * INNER / 8);

    // attention: 1664 blocks (TLP), barrier-free main loop
    attn_mfma_k<<<dim3(NHEAD * BATCH, 13), 256, 0, stream>>>(Yb, bias, idxs, Ob);

    // GEMM2 (+fused BN2 stats): out = O_hsw @ Wproj^T
    gemm_mfma_k<1, 0, 0, 0><<<dim3(CDIM / 128, R_TOTAL / 128), 256, 0, stream>>>(
        Ob, Wproj, out, S2, R_TOTAL, CDIM, CDIM);

    finalize_bn_k<<<(CDIM + 255) / 256, 256, 0, stream>>>(
        S2, g2, b2, AB2, CDIM, 1.f / R_TOTAL, 0, 0, 1.f);
    bn_apply_k<<<1024, 256, 0, stream>>>(out, AB2, CDIM, (R_TOTAL * CDIM) / 4);
}

// Round 3
// 241.007 us; speedup vs baseline: 1.0621x; 1.0621x over previous
//
#include <hip/hip_runtime.h>

#define R_TOTAL 12544
#define NTOK    784
#define CDIM    384
#define INNER   1152
#define NHEAD   8
#define HDIM    48
#define BATCH   16
#define HSEG    37632                  // 784*48 elements per (b,h,part) panel
#define SCALE   0.14433756729740643f   // 48^-0.5
#define LOG2E   1.4426950408889634f
#define SCLOG2E 0.20823509f            // SCALE * LOG2E (folded into K's BN affine)

typedef unsigned short u16;
typedef unsigned int   u32;
typedef __attribute__((ext_vector_type(8))) short short8;   // 8 bf16, 4 VGPRs
typedef __attribute__((ext_vector_type(4))) float floatx4;  // MFMA C/D

union V8 { uint4 u; short8 s; u16 h[8]; };

// workspace layout (BYTE offsets) — total 38.56 MB, unchanged.
// Yb is HEAD-MAJOR: [b][h][{q,k,v}] panels of HSEG elements each.
//   q,k panels: [n=784][d=48] row-major
//   v panel:    TRANSPOSED [d=48][n=784]  (attention PV A-frags load directly)
// Region reuse across time (stream-ordered, no overlap at any instant):
//   OB_OFF region: xb (bf16 x) during GEMM1  ->  Ob (attn output) afterwards
//   d_out  region: Wqkv-bf16 during GEMM1    ->  final output at the end
//   Yb base:       Q/K/V panels until attn   ->  Wproj-bf16 for GEMM2
#define OB_OFF     28901376ull   // Ob bf16 [12544,384]  (== xb during GEMM1)
#define ST_OFF     38535168ull   // fp32 stats: S1[2304] AB1[2304] S2[768] AB2[768]

__device__ __forceinline__ float b2f(u16 u) {
    union { float f; u32 i; } v; v.i = ((u32)u) << 16; return v.f;
}
__device__ __forceinline__ u16 f2b(float f) {
    union { float f; u32 i; } v; v.f = f;
    u32 r = v.i + 0x7FFFu + ((v.i >> 16) & 1u);   // RNE
    return (u16)(r >> 16);
}
// pack two fp32 -> two bf16 (RNE) in one v_perm_b32
__device__ __forceinline__ u32 pk2(float lo, float hi) {
    union { float f; u32 i; } a, b; a.f = lo; b.f = hi;
    u32 ra = a.i + 0x7FFFu + ((a.i >> 16) & 1u);
    u32 rb = b.i + 0x7FFFu + ((b.i >> 16) & 1u);
    return __builtin_amdgcn_perm(rb, ra, 0x07060302u);   // [rb.hi16 : ra.hi16]
}
__device__ __forceinline__ float hswish_f(float v) {
    return v * fminf(fmaxf(v + 3.f, 0.f), 6.f) * (1.f / 6.f);
}

// async global->LDS, 16B per lane (linear dest: wave-uniform base + lane*16)
__device__ __forceinline__ void gll16(const void* g, void* l) {
    __builtin_amdgcn_global_load_lds(
        (const __attribute__((address_space(1))) void*)g,
        (__attribute__((address_space(3))) void*)l, 16, 0, 0);
}

__global__ __launch_bounds__(256) void zero_k(float* __restrict__ p, int n) {
    int i = blockIdx.x * 256 + threadIdx.x;
    if (i < n) p[i] = 0.f;
}

// fp32 -> bf16 convert, 8 elems/thread
__global__ __launch_bounds__(256) void cvt8_k(
    const float* __restrict__ src, u16* __restrict__ dst, int total8)
{
    int i = blockIdx.x * 256 + threadIdx.x;
    if (i >= total8) return;
    const float* p = src + (size_t)i * 8;
    float4 f0 = *(const float4*)p, f1 = *(const float4*)(p + 4);
    uint4 o;
    o.x = pk2(f0.x, f0.y); o.y = pk2(f0.z, f0.w);
    o.z = pk2(f1.x, f1.y); o.w = pk2(f1.z, f1.w);
    *(uint4*)(dst + (size_t)i * 8) = o;
}

// ---------------------------------------------------------------- bf16 x bf16 MFMA GEMM
// m97 structure: global_load_lds (16B) into LINEAR [128][32] LDS tiles, 2 barriers/k-step.
// Fused BN column stats; HEADM epilogue (head-major + transposed V panel) for GEMM1.
template<int OBF16, int HEADM>
__global__ __launch_bounds__(256) void gemm_bb_k(
    const u16* __restrict__ A, const u16* __restrict__ B,
    void* __restrict__ Cp, float* __restrict__ sums, int Nout, int K)
{
    __shared__ u16 As[128 * 32];
    __shared__ u16 Bs[128 * 32];
    const int t = threadIdx.x;
    const int lane = t & 63, wv = t >> 6;
    const int l15 = lane & 15, quad = lane >> 4;
    const int wm = (wv & 1) * 64, wn = (wv >> 1) * 64;
    const int m0 = blockIdx.y * 128, n0 = blockIdx.x * 128;
    const floatx4 zf = {0.f, 0.f, 0.f, 0.f};

    floatx4 acc[4][4];
    #pragma unroll
    for (int i = 0; i < 4; i++)
        #pragma unroll
        for (int j = 0; j < 4; j++) acc[i][j] = zf;

    for (int k0 = 0; k0 < K; k0 += 32) {
        __syncthreads();                    // previous tile's frags consumed
        #pragma unroll
        for (int it = 0; it < 2; it++) {
            const int flat = t + it * 256;
            const int rr = flat >> 2, ss = (flat & 3) * 8;
            gll16(A + (size_t)(m0 + rr) * K + k0 + ss, As + (size_t)flat * 8);
            gll16(B + (size_t)(n0 + rr) * K + k0 + ss, Bs + (size_t)flat * 8);
        }
        asm volatile("s_waitcnt vmcnt(0)" ::: "memory");
        __syncthreads();
        short8 af[4], bfr[4];
        #pragma unroll
        for (int mi = 0; mi < 4; mi++)
            af[mi] = *(const short8*)&As[(wm + mi * 16 + l15) * 32 + quad * 8];
        #pragma unroll
        for (int ni = 0; ni < 4; ni++)
            bfr[ni] = *(const short8*)&Bs[(wn + ni * 16 + l15) * 32 + quad * 8];
        #pragma unroll
        for (int mi = 0; mi < 4; mi++)
            #pragma unroll
            for (int ni = 0; ni < 4; ni++)
                acc[mi][ni] = __builtin_amdgcn_mfma_f32_16x16x32_bf16(af[mi], bfr[ni], acc[mi][ni], 0, 0, 0);
    }

    float cs[4] = {0.f, 0.f, 0.f, 0.f}, cq[4] = {0.f, 0.f, 0.f, 0.f};
    #pragma unroll
    for (int mi = 0; mi < 4; mi++) {
        const int mbase = m0 + wm + mi * 16 + quad * 4;
        int bb_[4], nn_[4];
        if (HEADM) {
            #pragma unroll
            for (int reg = 0; reg < 4; reg++) {
                int m = mbase + reg;
                int bv = ((m >> 4) * 1338) >> 16;   // m/784 for m<12544 (=16*49; x/49=(x*1338)>>16)
                bb_[reg] = bv;
                nn_[reg] = m - bv * 784;
            }
        }
        #pragma unroll
        for (int ni = 0; ni < 4; ni++) {
            const int c0 = n0 + wn + ni * 16;      // wave-uniform; 16-col group never straddles h
            const int n = c0 + l15;
            int part = 0, hcol = 0, d0 = 0;
            if (HEADM) {
                part = c0 / 384;
                int rem = c0 - part * 384;
                hcol = rem / 48;
                d0 = rem - hcol * 48;
            }
            if (HEADM && part == 2) {
                // V panel TRANSPOSED: [d][n]; 4 regs = 4 consecutive n (same b: mbase%4==0, 784%4==0)
                u32 w0 = pk2(acc[mi][ni][0], acc[mi][ni][1]);
                u32 w1 = pk2(acc[mi][ni][2], acc[mi][ni][3]);
                size_t off = (size_t)((bb_[0] * 8 + hcol) * 3 + 2) * HSEG
                           + (size_t)(d0 + l15) * NTOK + nn_[0];
                *(uint2*)((u16*)Cp + off) = make_uint2(w0, w1);
                float v0 = b2f((u16)(w0 & 0xffff)), v1 = b2f((u16)(w0 >> 16));
                float v2 = b2f((u16)(w1 & 0xffff)), v3 = b2f((u16)(w1 >> 16));
                cs[ni] += (v0 + v1) + (v2 + v3);
                cq[ni] += (v0 * v0 + v1 * v1) + (v2 * v2 + v3 * v3);
            } else {
                #pragma unroll
                for (int reg = 0; reg < 4; reg++) {
                    float v = acc[mi][ni][reg];
                    float vv;
                    if (OBF16) {
                        u16 hv = f2b(v);
                        size_t off;
                        if (HEADM)
                            off = (size_t)((bb_[reg] * 8 + hcol) * 3 + part) * HSEG
                                + (size_t)nn_[reg] * 48 + d0 + l15;
                        else
                            off = (size_t)(mbase + reg) * Nout + n;
                        ((u16*)Cp)[off] = hv;
                        vv = b2f(hv);
                    } else {
                        ((float*)Cp)[(size_t)(mbase + reg) * Nout + n] = v;
                        vv = v;
                    }
                    cs[ni] += vv;
                    cq[ni] += vv * vv;
                }
            }
        }
    }
    #pragma unroll
    for (int ni = 0; ni < 4; ni++) {
        float s = cs[ni], sq = cq[ni];
        s  += __shfl_xor(s, 16);  s  += __shfl_xor(s, 32);
        sq += __shfl_xor(sq, 16); sq += __shfl_xor(sq, 32);
        if (quad == 0) {
            int col = n0 + wn + ni * 16 + l15;
            atomicAdd(&sums[col], s);
            atomicAdd(&sums[Nout + col], sq);
        }
    }
}

// sc0..sc1: logical-column range whose affine is pre-scaled by sfac (K cols: SCALE*log2e)
__global__ __launch_bounds__(256) void finalize_bn_k(
    const float* __restrict__ sums, const float* __restrict__ g,
    const float* __restrict__ bvec, float* __restrict__ ab, int Ncols, float invM,
    int sc0, int sc1, float sfac)
{
    int c = blockIdx.x * 256 + threadIdx.x;
    if (c >= Ncols) return;
    float mean = sums[c] * invM;
    float var  = sums[Ncols + c] * invM - mean * mean;
    float a    = g[c] * rsqrtf(var + 1e-5f);
    float f    = (c >= sc0 && c < sc1) ? sfac : 1.f;
    ab[c] = a * f;
    ab[Ncols + c] = (bvec[c] - mean * a) * f;
}

__global__ __launch_bounds__(256) void bn_apply_k(
    float* __restrict__ Z, const float* __restrict__ ab, int Ncols, int total4)
{
    for (int i4 = blockIdx.x * 256 + threadIdx.x; i4 < total4; i4 += gridDim.x * 256) {
        int col = (i4 * 4) % Ncols;
        float4 z  = *(float4*)(Z + (size_t)i4 * 4);
        float4 a4 = *(const float4*)(ab + col);
        float4 b4 = *(const float4*)(ab + Ncols + col);
        z.x = a4.x * z.x + b4.x; z.y = a4.y * z.y + b4.y;
        z.z = a4.z * z.z + b4.z; z.w = a4.w * z.w + b4.w;
        *(float4*)(Z + (size_t)i4 * 4) = z;
    }
}

// bf16 in-place BN apply over HEAD-MAJOR Y: logical col derived from physical index.
// q,k panels: [n][d]; v panel: TRANSPOSED [d][n] (8 consecutive elems share one d/col).
__global__ __launch_bounds__(256) void bn_apply_bf16_k(
    u16* __restrict__ Z, const float* __restrict__ ab, int total8)
{
    int i8 = blockIdx.x * 256 + threadIdx.x;
    if (i8 >= total8) return;
    int e0  = i8 * 8;
    int seg = e0 / HSEG;                 // (b*8+h)*3 + part
    int rem = e0 - seg * HSEG;
    int part = seg % 3;
    int hh   = (seg / 3) & 7;
    uint4 u = *(uint4*)(Z + (size_t)i8 * 8);
    uint4 o;
    if (part == 2) {
        int dd  = rem / NTOK;            // row d (8 consecutive n in one d row)
        int col = 2 * 384 + hh * 48 + dd;
        float a = ab[col], bb = ab[1152 + col];
        o.x = pk2(fmaf(b2f((u16)(u.x & 0xffff)), a, bb), fmaf(b2f((u16)(u.x >> 16)), a, bb));
        o.y = pk2(fmaf(b2f((u16)(u.y & 0xffff)), a, bb), fmaf(b2f((u16)(u.y >> 16)), a, bb));
        o.z = pk2(fmaf(b2f((u16)(u.z & 0xffff)), a, bb), fmaf(b2f((u16)(u.z >> 16)), a, bb));
        o.w = pk2(fmaf(b2f((u16)(u.w & 0xffff)), a, bb), fmaf(b2f((u16)(u.w >> 16)), a, bb));
    } else {
        int d0  = rem % 48;
        int col = part * 384 + hh * 48 + d0;
        float4 A0 = *(const float4*)(ab + col),        A1 = *(const float4*)(ab + col + 4);
        float4 B0 = *(const float4*)(ab + 1152 + col), B1 = *(const float4*)(ab + 1152 + col + 4);
        o.x = pk2(fmaf(b2f((u16)(u.x & 0xffff)), A0.x, B0.x), fmaf(b2f((u16)(u.x >> 16)), A0.y, B0.y));
        o.y = pk2(fmaf(b2f((u16)(u.y & 0xffff)), A0.z, B0.z), fmaf(b2f((u16)(u.y >> 16)), A0.w, B0.w));
        o.z = pk2(fmaf(b2f((u16)(u.z & 0xffff)), A1.x, B1.x), fmaf(b2f((u16)(u.z >> 16)), A1.y, B1.y));
        o.w = pk2(fmaf(b2f((u16)(u.w & 0xffff)), A1.z, B1.z), fmaf(b2f((u16)(u.w >> 16)), A1.w, B1.w));
    }
    *(uint4*)(Z + (size_t)i8 * 8) = o;
}

// ---------------------------------------------------------------- MFMA flash attention v8 (REVERT)
// V stored pre-transposed by GEMM1 -> PV A-frags load straight from global (L2-resident).
// Main loop is BARRIER-FREE: psm is wave-local, hb is read-only after one initial barrier.
// Measured 83 µs (round 1); the TLP variant (round 2) regressed to 96 µs.
__global__ __launch_bounds__(256) void attn_mfma_k(
    const u16* __restrict__ Y,
    const float* __restrict__ biases, const int* __restrict__ idxs,
    u16* __restrict__ O)
{
    __shared__ u16 psm[4][2][2 * 64 * 8];   // per-wave, per-q-half P^T (16 KB)
    __shared__ float hb[NTOK];              // biases[h] * LOG2E

    const int t = threadIdx.x;
    const int lane = t & 63, wv = t >> 6;
    const int l15 = lane & 15, quad = lane >> 4;
    const int bh = blockIdx.x;
    const int b = bh >> 3, h = bh & 7;
    const int n0 = blockIdx.y * 128;
    const int bN = b * NTOK;
    const floatx4 zf = {0.f, 0.f, 0.f, 0.f};

    const u16* Qb = Y + (size_t)(bh * 3) * HSEG;
    const u16* Kb = Qb + HSEG;
    const u16* Vb = Qb + 2 * HSEG;          // TRANSPOSED [48][784]

    if (t < 196) {
        float4 v = *(const float4*)(biases + (size_t)h * NTOK + (t << 2));
        v.x *= LOG2E; v.y *= LOG2E; v.z *= LOG2E; v.w *= LOG2E;
        *(float4*)&hb[t << 2] = v;
    }

    int qv[2], qr[2];
    #pragma unroll
    for (int qh = 0; qh < 2; qh++) {
        qv[qh] = n0 + qh * 64 + wv * 16 + l15;
        qr[qh] = qv[qh] < NTOK ? qv[qh] : NTOK - 1;
    }
    const int* idxrow[2] = { idxs + (size_t)qr[0] * NTOK, idxs + (size_t)qr[1] * NTOK };

    // Q B-frags: B[k=d][n=q=l15]; chunk1 zero for quad>=2 (d pad 48..63)
    short8 qf[2][2];
    #pragma unroll
    for (int qh = 0; qh < 2; qh++) {
        V8 a0, a1;
        a1.u = make_uint4(0u, 0u, 0u, 0u);
        const u16* src = Qb + (size_t)qr[qh] * 48;
        a0.u = *(const uint4*)(src + quad * 8);
        if (quad < 2) a1.u = *(const uint4*)(src + 32 + quad * 8);
        qf[qh][0] = a0.s; qf[qh][1] = a1.s;
    }

    // preload K A-frags for tile 0
    V8 kfr[4][2];
    #pragma unroll
    for (int sub = 0; sub < 4; sub++) {
        const u16* src = Kb + (size_t)(sub * 16 + l15) * 48;
        kfr[sub][0].u = *(const uint4*)(src + quad * 8);
        kfr[sub][1].u = *(const uint4*)(src + 32 + quad * 8);  // quad>=2: next-row bf16, x0 on B side
    }

    float lsum[2] = {0.f, 0.f};
    floatx4 oacc[2][3];
    #pragma unroll
    for (int qh = 0; qh < 2; qh++)
        #pragma unroll
        for (int i = 0; i < 3; i++) oacc[qh][i] = zf;

    const int psbase = ((quad >> 1) * 16 + l15) * 8 + (quad & 1) * 4;

    __syncthreads();   // hb staged; the ONLY barrier in this kernel

    for (int mt = 0; mt < 13; mt++) {
        const int m0k = mt * 64;
        const bool tail = (m0k == 768);

        // ---- idx gathers for THIS tile (issued first; consumed after QK)
        int4 ivc[2][4];
        #pragma unroll
        for (int qh = 0; qh < 2; qh++)
            #pragma unroll
            for (int sub = 0; sub < 4; sub++) {
                int kb = m0k + sub * 16 + quad * 4;
                kb = kb < NTOK - 4 ? kb : NTOK - 4;
                ivc[qh][sub] = *(const int4*)(idxrow[qh] + kb);
            }

        // ---- V^T A-frags for THIS tile, direct from global (consumed at PV)
        // A[m=d=l15][k=key=quad*8+j]. Tail: keys>=784 -> clamp addr to key 0 (P=0 there).
        short8 vfr[2][3];
        #pragma unroll
        for (int kc = 0; kc < 2; kc++) {
            int kk = m0k + kc * 32 + quad * 8;
            kk = kk <= NTOK - 8 ? kk : 0;
            #pragma unroll
            for (int ns = 0; ns < 3; ns++)
                vfr[kc][ns] = *(const short8*)(Vb + (size_t)(ns * 16 + l15) * NTOK + kk);
        }

        // ---- prefetch K(mt+1) into regs
        V8 kn[4][2];
        const bool more = (mt + 1 < 13);
        if (more) {
            const int mn = m0k + 64;
            #pragma unroll
            for (int sub = 0; sub < 4; sub++) {
                int key = mn + sub * 16 + l15;
                int kr  = key < NTOK ? key : NTOK - 1;
                const u16* src = Kb + (size_t)kr * 48;
                kn[sub][0].u = *(const uint4*)(src + quad * 8);
                kn[sub][1].u = *(const uint4*)(src + 32 + quad * 8);
            }
        }

        // ---- per q-half: S^T = K*Q^T, then p = 2^(s + bias)
        #pragma unroll
        for (int qh = 0; qh < 2; qh++) {
            floatx4 sf[4];
            #pragma unroll
            for (int sub = 0; sub < 4; sub++) {
                floatx4 c = zf;
                c = __builtin_amdgcn_mfma_f32_16x16x32_bf16(kfr[sub][0].s, qf[qh][0], c, 0, 0, 0);
                c = __builtin_amdgcn_mfma_f32_16x16x32_bf16(kfr[sub][1].s, qf[qh][1], c, 0, 0, 0);
                sf[sub] = c;
            }
            #pragma unroll
            for (int sub = 0; sub < 4; sub++) {
                const int4 iv = ivc[qh][sub];
                float a0 = sf[sub][0] + hb[iv.x];
                float a1 = sf[sub][1] + hb[iv.y];
                float a2 = sf[sub][2] + hb[iv.z];
                float a3 = sf[sub][3] + hb[iv.w];
                float pr[4];
                asm("v_exp_f32 %0, %1" : "=v"(pr[0]) : "v"(a0));
                asm("v_exp_f32 %0, %1" : "=v"(pr[1]) : "v"(a1));
                asm("v_exp_f32 %0, %1" : "=v"(pr[2]) : "v"(a2));
                asm("v_exp_f32 %0, %1" : "=v"(pr[3]) : "v"(a3));
                if (tail) {   // wave-uniform: only tile 12 has keys >= 784
                    const int kb0 = m0k + sub * 16 + quad * 4;
                    #pragma unroll
                    for (int reg = 0; reg < 4; reg++)
                        if (kb0 + reg >= NTOK) pr[reg] = 0.f;
                }
                lsum[qh] += (pr[0] + pr[1]) + (pr[2] + pr[3]);
                int addr = psbase + (sub >> 1) * 512 + (sub & 1) * 256;
                *(uint2*)&psm[wv][qh][addr] = make_uint2(pk2(pr[0], pr[1]), pk2(pr[2], pr[3]));
            }
        }

        // ---- O^T += V^T * P^T (V frags shared across q-halves; wave-local LDS, no barrier)
        #pragma unroll
        for (int kc = 0; kc < 2; kc++) {
            short8 pb0 = *(const short8*)&psm[wv][0][(kc * 64 + lane) * 8];
            short8 pb1 = *(const short8*)&psm[wv][1][(kc * 64 + lane) * 8];
            #pragma unroll
            for (int ns = 0; ns < 3; ns++) {
                oacc[0][ns] = __builtin_amdgcn_mfma_f32_16x16x32_bf16(vfr[kc][ns], pb0, oacc[0][ns], 0, 0, 0);
                oacc[1][ns] = __builtin_amdgcn_mfma_f32_16x16x32_bf16(vfr[kc][ns], pb1, oacc[1][ns], 0, 0, 0);
            }
        }

        // ---- rotate K pipeline
        if (more) {
            #pragma unroll
            for (int sub = 0; sub < 4; sub++) {
                kfr[sub][0] = kn[sub][0];
                kfr[sub][1] = kn[sub][1];
            }
        }
    }

    // ---- epilogue (Ob stays row-major [12544,384] for GEMM2)
    #pragma unroll
    for (int qh = 0; qh < 2; qh++) {
        float ls = lsum[qh];
        ls += __shfl_xor(ls, 16);
        ls += __shfl_xor(ls, 32);
        if (qv[qh] < NTOK) {
            float rl = 1.f / ls;
            u16* dst = O + (size_t)(bN + qv[qh]) * CDIM + h * HDIM;
            #pragma unroll
            for (int ns = 0; ns < 3; ns++)
                #pragma unroll
                for (int reg = 0; reg < 4; reg++)
                    dst[ns * 16 + quad * 4 + reg] = f2b(hswish_f(oacc[qh][ns][reg] * rl));
        }
    }
}

// ---------------------------------------------------------------- launch
extern "C" void kernel_launch(void* const* d_in, const int* in_sizes, int n_in,
                              void* d_out, int out_size, void* d_ws, size_t ws_size,
                              hipStream_t stream)
{
    const float* x     = (const float*)d_in[0];
    const float* Wqkv  = (const float*)d_in[1];
    const float* g1    = (const float*)d_in[2];
    const float* b1    = (const float*)d_in[3];
    const float* Wproj = (const float*)d_in[4];
    const float* g2    = (const float*)d_in[5];
    const float* b2    = (const float*)d_in[6];
    const float* bias  = (const float*)d_in[7];
    const int*   idxs  = (const int*)d_in[8];
    float* out = (float*)d_out;
    char*  wsb = (char*)d_ws;

    u16*   Yb  = (u16*)wsb;
    u16*   Ob  = (u16*)(wsb + OB_OFF);
    float* S1  = (float*)(wsb + ST_OFF);
    float* AB1 = S1 + 2304;
    float* S2  = AB1 + 2304;
    float* AB2 = S2 + 768;

    // bf16 copies (region reuse, no workspace growth):
    u16* xb  = (u16*)(wsb + OB_OFF);   // x bf16; region becomes Ob after attn
    u16* wqb = (u16*)d_out;            // Wqkv bf16; region becomes out after GEMM2
    u16* wpb = (u16*)wsb;              // Wproj bf16 over dead Yb (after attn)

    // pre-convert x and Wqkv to bf16 (one-time; GEMM staging becomes global_load_lds)
    cvt8_k<<<(R_TOTAL * CDIM / 8 + 255) / 256, 256, 0, stream>>>(x, xb, R_TOTAL * CDIM / 8);
    cvt8_k<<<(INNER * CDIM / 8 + 255) / 256, 256, 0, stream>>>(Wqkv, wqb, INNER * CDIM / 8);
    zero_k<<<24, 256, 0, stream>>>(S1, 6144);

    // GEMM1 (+fused BN1 stats), head-major output, V panels transposed
    gemm_bb_k<1, 1><<<dim3(INNER / 128, R_TOTAL / 128), 256, 0, stream>>>(
        xb, wqb, Yb, S1, INNER, CDIM);

    finalize_bn_k<<<(INNER + 255) / 256, 256, 0, stream>>>(
        S1, g1, b1, AB1, INNER, 1.f / R_TOTAL, CDIM, 2 * CDIM, SCLOG2E);
    bn_apply_bf16_k<<<(R_TOTAL * INNER / 8 + 255) / 256, 256, 0, stream>>>(
        Yb, AB1, R_TOTAL * INNER / 8);

    // attention (xb dead from here; writes Ob into that region)
    attn_mfma_k<<<dim3(NHEAD * BATCH, 7), 256, 0, stream>>>(Yb, bias, idxs, Ob);

    // Wproj -> bf16 into dead Yb region, then GEMM2 (+fused BN2 stats)
    cvt8_k<<<(CDIM * CDIM / 8 + 255) / 256, 256, 0, stream>>>(Wproj, wpb, CDIM * CDIM / 8);
    gemm_bb_k<0, 0><<<dim3(CDIM / 128, R_TOTAL / 128), 256, 0, stream>>>(
        Ob, wpb, out, S2, CDIM, CDIM);

    finalize_bn_k<<<(CDIM + 255) / 256, 256, 0, stream>>>(
        S2, g2, b2, AB2, CDIM, 1.f / R_TOTAL, 0, 0, 1.f);
    bn_apply_k<<<1024, 256, 0, stream>>>(out, AB2, CDIM, (R_TOTAL * CDIM) / 4);
}